// Round 3
// baseline (299.953 us; speedup 1.0000x reference)
//
#include <hip/hip_runtime.h>

#define NP 15
#define NK 17
#define HH 256
#define WW 256
#define TPB 256
#define BLOCKS 4080                     // 4080*256 threads * 4 float4 = 4,177,920 = n/4 exactly
#define NTHREADS ((size_t)BLOCKS * TPB) // 1,044,480

typedef float f32x4 __attribute__((ext_vector_type(4)));

__device__ __forceinline__ float softplus(float x) {
    return fmaxf(x, 0.f) + __logf(1.f + __expf(-fabsf(x)));
}

// ws: ws[0]=softplus sum (f64), ws[1]=weighted disk sum (f64), counter at ws+2
__global__ __launch_bounds__(256) void fused_loss_kernel(
    const f32x4* __restrict__ x4, const float* __restrict__ pred,
    const float* __restrict__ kp, double* __restrict__ ws,
    unsigned int* __restrict__ wcount, float* __restrict__ out) {
    const int tid = threadIdx.x;
    const size_t base = (size_t)blockIdx.x * TPB + tid;

    // ---- 4 independent coalesced float4 loads, all in flight before any wait ----
    const f32x4* p0 = x4 + base;
    const f32x4* p1 = p0 + NTHREADS;
    const f32x4* p2 = p0 + 2 * NTHREADS;
    const f32x4* p3 = p0 + 3 * NTHREADS;
    f32x4 v0, v1, v2, v3;
    asm volatile("global_load_dwordx4 %0, %1, off" : "=v"(v0) : "v"(p0));
    asm volatile("global_load_dwordx4 %0, %1, off" : "=v"(v1) : "v"(p1));
    asm volatile("global_load_dwordx4 %0, %1, off" : "=v"(v2) : "v"(p2));
    asm volatile("global_load_dwordx4 %0, %1, off" : "=v"(v3) : "v"(p3));
    // Single drain; "+v" ties the values through the asm so uses can't hoist.
    asm volatile("s_waitcnt vmcnt(0)"
                 : "+v"(v0), "+v"(v1), "+v"(v2), "+v"(v3));

    float a0 = softplus(v0.x) + softplus(v0.y) + softplus(v0.z) + softplus(v0.w);
    float a1 = softplus(v1.x) + softplus(v1.y) + softplus(v1.z) + softplus(v1.w);
    float a2 = softplus(v2.x) + softplus(v2.y) + softplus(v2.z) + softplus(v2.w);
    float a3 = softplus(v3.x) + softplus(v3.y) + softplus(v3.z) + softplus(v3.w);
    float acc = (a0 + a1) + (a2 + a3);

    // ---- keypoint disk sums: blocks 0..254, wave 0, one masked load each ----
    float dsum = 0.f;
    if (blockIdx.x < NP * NK && tid < 64) {
        const int t = blockIdx.x;            // keypoint index p*NK + k
        const float xf = kp[2 * t];
        const float yf = kp[2 * t + 1];
        const bool valid =
            ((xf != 0.f) && (xf != -1.f)) || ((yf != 0.f) && (yf != -1.f));
        if (valid && tid < 49) {
            const int dy = tid / 7 - 3;
            const int dx = tid % 7 - 3;
            if (dy * dy + dx * dx <= 9) {
                const int yy = (int)yf + dy;   // trunc matches astype(int32)
                const int xx = (int)xf + dx;
                if (yy >= 0 && yy < HH && xx >= 0 && xx < WW)
                    dsum = pred[(size_t)t * (HH * WW) + yy * WW + xx];
            }
        }
        #pragma unroll
        for (int off = 32; off > 0; off >>= 1)
            dsum += __shfl_down(dsum, off, 64);
        if (tid == 0) dsum *= (float)(NP - t / NK);
    }

    // ---- block reduce softplus partials ----
    #pragma unroll
    for (int off = 32; off > 0; off >>= 1)
        acc += __shfl_down(acc, off, 64);
    __shared__ float wsums[4];
    if ((tid & 63) == 0) wsums[tid >> 6] = acc;
    __syncthreads();

    if (tid == 0) {
        float btot = wsums[0] + wsums[1] + wsums[2] + wsums[3];
        atomicAdd(&ws[0], (double)btot);
        if (blockIdx.x < NP * NK) atomicAdd(&ws[1], (double)dsum);
        __threadfence();
        unsigned int old = atomicAdd(wcount, 1u);
        if (old == BLOCKS - 1) {
            double ssum = atomicAdd(&ws[0], 0.0);   // coherent read-back
            double wsum = atomicAdd(&ws[1], 0.0);
            const double N = (double)NP * NK * HH * WW;
            double heatmap_loss = ssum / N - wsum / ((double)NP * N);
            out[0] = (float)(4.0 * heatmap_loss + 0.02);
        }
    }
}

extern "C" void kernel_launch(void* const* d_in, const int* in_sizes, int n_in,
                              void* d_out, int out_size, void* d_ws, size_t ws_size,
                              hipStream_t stream) {
    const float* pred = (const float*)d_in[0];   // [15,17,256,256] fp32
    const float* kp   = (const float*)d_in[2];   // [15,17,2] fp32
    float* out = (float*)d_out;
    double* ws = (double*)d_ws;
    unsigned int* wcount = (unsigned int*)(ws + 2);

    hipMemsetAsync(d_ws, 0, 24, stream);         // ws is 0xAA-poisoned every call

    fused_loss_kernel<<<BLOCKS, TPB, 0, stream>>>(
        (const f32x4*)pred, pred, kp, ws, wcount, out);
}

// Round 4
// 150.983 us; speedup vs baseline: 1.9867x; 1.9867x over previous
//
#include <hip/hip_runtime.h>

#define NP 15
#define NK 17
#define HH 256
#define WW 256
#define TPB 256
#define BLOCKS_A 1020   // 1020 * 256 threads * 16 float4 = 4,177,920 = NP*NK*HH*WW/4 exactly
#define ITERS 16

typedef float f32x4 __attribute__((ext_vector_type(4)));

__device__ __forceinline__ float softplus(float x) {
    return fmaxf(x, 0.f) + __logf(1.f + __expf(-fabsf(x)));
}

// ---------------- Kernel A: per-block softplus partials (NO atomics) --------
__global__ __launch_bounds__(256) void softplus_partial_kernel(
    const f32x4* __restrict__ x4, float* __restrict__ partials) {
    const int tid = threadIdx.x;
    const size_t base = (size_t)blockIdx.x * (TPB * ITERS) + tid;

    float acc = 0.f;
    #pragma unroll
    for (int k = 0; k < ITERS; ++k) {
        f32x4 v = x4[base + (size_t)k * TPB];
        acc += softplus(v.x) + softplus(v.y) + softplus(v.z) + softplus(v.w);
    }

    #pragma unroll
    for (int off = 32; off > 0; off >>= 1)
        acc += __shfl_down(acc, off, 64);
    __shared__ float wsums[4];
    if ((tid & 63) == 0) wsums[tid >> 6] = acc;
    __syncthreads();
    if (tid == 0)
        partials[blockIdx.x] = wsums[0] + wsums[1] + wsums[2] + wsums[3];
}

// ---------------- Kernel B: finisher (1 block, no atomics) ------------------
__global__ __launch_bounds__(256) void finish_kernel(
    const float* __restrict__ pred, const float* __restrict__ kp,
    const float* __restrict__ partials, float* __restrict__ out) {
    const int tid = threadIdx.x;

    // sum the 1020 block partials: 4 strided loads per thread
    float ssum = 0.f;
    #pragma unroll
    for (int j = 0; j < 4; ++j) {
        int i = tid + j * TPB;
        if (i < BLOCKS_A) ssum += partials[i];
    }

    // keypoint disk sums: thread t handles keypoint t
    float dsum = 0.f;
    if (tid < NP * NK) {
        const float xf = kp[2 * tid];
        const float yf = kp[2 * tid + 1];
        const bool valid =
            ((xf != 0.f) && (xf != -1.f)) || ((yf != 0.f) && (yf != -1.f));
        if (valid) {
            const int xi = (int)xf;   // truncation matches astype(int32)
            const int yi = (int)yf;
            const float* basep = pred + (size_t)tid * (HH * WW);
            float s = 0.f;
            #pragma unroll
            for (int dy = -3; dy <= 3; ++dy) {
                const int yy = yi + dy;
                if (yy < 0 || yy >= HH) continue;
                #pragma unroll
                for (int dx = -3; dx <= 3; ++dx) {
                    if (dy * dy + dx * dx > 9) continue;
                    const int xx = xi + dx;
                    if (xx < 0 || xx >= WW) continue;
                    s += basep[yy * WW + xx];
                }
            }
            dsum = (float)(NP - tid / NK) * s;
        }
    }

    // block-reduce both sums
    #pragma unroll
    for (int off = 32; off > 0; off >>= 1) {
        ssum += __shfl_down(ssum, off, 64);
        dsum += __shfl_down(dsum, off, 64);
    }
    __shared__ float sred[4], dred[4];
    if ((tid & 63) == 0) { sred[tid >> 6] = ssum; dred[tid >> 6] = dsum; }
    __syncthreads();

    if (tid == 0) {
        double stot = (double)(sred[0] + sred[1]) + (double)(sred[2] + sred[3]);
        double dtot = (double)(dred[0] + dred[1]) + (double)(dred[2] + dred[3]);
        const double N = (double)NP * NK * HH * WW;
        double heatmap_loss = stot / N - dtot / ((double)NP * N);
        out[0] = (float)(4.0 * heatmap_loss + 0.02);
    }
}

extern "C" void kernel_launch(void* const* d_in, const int* in_sizes, int n_in,
                              void* d_out, int out_size, void* d_ws, size_t ws_size,
                              hipStream_t stream) {
    const float* pred = (const float*)d_in[0];   // [15,17,256,256] fp32
    const float* kp   = (const float*)d_in[2];   // [15,17,2] fp32
    float* out = (float*)d_out;
    float* partials = (float*)d_ws;              // 1020 floats, fully written by A

    softplus_partial_kernel<<<BLOCKS_A, TPB, 0, stream>>>(
        (const f32x4*)pred, partials);
    finish_kernel<<<1, TPB, 0, stream>>>(pred, kp, partials, out);
}

// Round 5
// 147.710 us; speedup vs baseline: 2.0307x; 1.0222x over previous
//
#include <hip/hip_runtime.h>

#define NP 15
#define NK 17
#define HH 256
#define WW 256
#define TPB 256
#define BLOCKS_A 2040   // 2040 * 256 threads * 8 float4 = 4,177,920 = NP*NK*HH*WW/4 exactly
#define ITERS 8

typedef float f32x4 __attribute__((ext_vector_type(4)));

__device__ __forceinline__ float softplus(float x) {
    return fmaxf(x, 0.f) + __logf(1.f + __expf(-fabsf(x)));
}

// ---------------- Kernel A: per-block softplus partials (no atomics) --------
__global__ __launch_bounds__(256) void softplus_partial_kernel(
    const f32x4* __restrict__ x4, float* __restrict__ partials) {
    const int tid = threadIdx.x;
    const size_t base = (size_t)blockIdx.x * (TPB * ITERS) + tid;

    // 4 independent accumulator chains -> no serializing dependency between
    // consecutive loads; compiler can keep several dwordx4 in flight.
    float a0 = 0.f, a1 = 0.f, a2 = 0.f, a3 = 0.f;
    #pragma unroll
    for (int k = 0; k < ITERS; k += 4) {
        f32x4 v0 = x4[base + (size_t)(k + 0) * TPB];
        f32x4 v1 = x4[base + (size_t)(k + 1) * TPB];
        f32x4 v2 = x4[base + (size_t)(k + 2) * TPB];
        f32x4 v3 = x4[base + (size_t)(k + 3) * TPB];
        a0 += softplus(v0.x) + softplus(v0.y) + softplus(v0.z) + softplus(v0.w);
        a1 += softplus(v1.x) + softplus(v1.y) + softplus(v1.z) + softplus(v1.w);
        a2 += softplus(v2.x) + softplus(v2.y) + softplus(v2.z) + softplus(v2.w);
        a3 += softplus(v3.x) + softplus(v3.y) + softplus(v3.z) + softplus(v3.w);
    }
    float acc = (a0 + a1) + (a2 + a3);

    #pragma unroll
    for (int off = 32; off > 0; off >>= 1)
        acc += __shfl_down(acc, off, 64);
    __shared__ float wsums[4];
    if ((tid & 63) == 0) wsums[tid >> 6] = acc;
    __syncthreads();
    if (tid == 0)
        partials[blockIdx.x] = wsums[0] + wsums[1] + wsums[2] + wsums[3];
}

// ---------------- Kernel B: finisher (1 block, no atomics) ------------------
__global__ __launch_bounds__(256) void finish_kernel(
    const float* __restrict__ pred, const float* __restrict__ kp,
    const float* __restrict__ partials, float* __restrict__ out) {
    const int tid = threadIdx.x;

    // sum the 2040 block partials: 8 strided loads per thread (2040 = 255*8)
    float ssum = 0.f;
    #pragma unroll
    for (int j = 0; j < 8; ++j) {
        int i = tid + j * TPB;
        if (i < BLOCKS_A) ssum += partials[i];
    }

    // keypoint disk sums: thread t handles keypoint t
    float dsum = 0.f;
    if (tid < NP * NK) {
        const float xf = kp[2 * tid];
        const float yf = kp[2 * tid + 1];
        const bool valid =
            ((xf != 0.f) && (xf != -1.f)) || ((yf != 0.f) && (yf != -1.f));
        if (valid) {
            const int xi = (int)xf;   // truncation matches astype(int32)
            const int yi = (int)yf;
            const float* basep = pred + (size_t)tid * (HH * WW);
            float s = 0.f;
            #pragma unroll
            for (int dy = -3; dy <= 3; ++dy) {
                const int yy = yi + dy;
                if (yy < 0 || yy >= HH) continue;
                #pragma unroll
                for (int dx = -3; dx <= 3; ++dx) {
                    if (dy * dy + dx * dx > 9) continue;
                    const int xx = xi + dx;
                    if (xx < 0 || xx >= WW) continue;
                    s += basep[yy * WW + xx];
                }
            }
            dsum = (float)(NP - tid / NK) * s;
        }
    }

    #pragma unroll
    for (int off = 32; off > 0; off >>= 1) {
        ssum += __shfl_down(ssum, off, 64);
        dsum += __shfl_down(dsum, off, 64);
    }
    __shared__ float sred[4], dred[4];
    if ((tid & 63) == 0) { sred[tid >> 6] = ssum; dred[tid >> 6] = dsum; }
    __syncthreads();

    if (tid == 0) {
        double stot = (double)(sred[0] + sred[1]) + (double)(sred[2] + sred[3]);
        double dtot = (double)(dred[0] + dred[1]) + (double)(dred[2] + dred[3]);
        const double N = (double)NP * NK * HH * WW;
        double heatmap_loss = stot / N - dtot / ((double)NP * N);
        out[0] = (float)(4.0 * heatmap_loss + 0.02);
    }
}

extern "C" void kernel_launch(void* const* d_in, const int* in_sizes, int n_in,
                              void* d_out, int out_size, void* d_ws, size_t ws_size,
                              hipStream_t stream) {
    const float* pred = (const float*)d_in[0];   // [15,17,256,256] fp32
    const float* kp   = (const float*)d_in[2];   // [15,17,2] fp32
    float* out = (float*)d_out;
    float* partials = (float*)d_ws;              // 2040 floats, fully written by A

    softplus_partial_kernel<<<BLOCKS_A, TPB, 0, stream>>>(
        (const f32x4*)pred, partials);
    finish_kernel<<<1, TPB, 0, stream>>>(pred, kp, partials, out);
}

// Round 6
// 139.099 us; speedup vs baseline: 2.1564x; 1.0619x over previous
//
#include <hip/hip_runtime.h>

#define NP 15
#define NK 17
#define HH 256
#define WW 256
#define TPB 256
#define BLOCKS_A 2040   // 2040 * 256 threads * 8 float4 = 4,177,920 = NP*NK*HH*WW/4 exactly
#define ITERS 8
#define NKP (NP * NK)   // 255

typedef float f32x4 __attribute__((ext_vector_type(4)));

__device__ __forceinline__ float softplus(float x) {
    return fmaxf(x, 0.f) + __logf(1.f + __expf(-fabsf(x)));
}

// ws layout: [0..2039] softplus block partials, [2048..2302] weighted disk sums
#define DSUM_OFF 2048

// ---- Kernel A: softplus partials + keypoint disk sums (plain stores only) ----
__global__ __launch_bounds__(256) void softplus_partial_kernel(
    const f32x4* __restrict__ x4, const float* __restrict__ pred,
    const float* __restrict__ kp, float* __restrict__ ws) {
    const int tid = threadIdx.x;
    const size_t base = (size_t)blockIdx.x * (TPB * ITERS) + tid;

    // 4 independent accumulator chains keep several dwordx4 in flight.
    float a0 = 0.f, a1 = 0.f, a2 = 0.f, a3 = 0.f;
    #pragma unroll
    for (int k = 0; k < ITERS; k += 4) {
        f32x4 v0 = x4[base + (size_t)(k + 0) * TPB];
        f32x4 v1 = x4[base + (size_t)(k + 1) * TPB];
        f32x4 v2 = x4[base + (size_t)(k + 2) * TPB];
        f32x4 v3 = x4[base + (size_t)(k + 3) * TPB];
        a0 += softplus(v0.x) + softplus(v0.y) + softplus(v0.z) + softplus(v0.w);
        a1 += softplus(v1.x) + softplus(v1.y) + softplus(v1.z) + softplus(v1.w);
        a2 += softplus(v2.x) + softplus(v2.y) + softplus(v2.z) + softplus(v2.w);
        a3 += softplus(v3.x) + softplus(v3.y) + softplus(v3.z) + softplus(v3.w);
    }
    float acc = (a0 + a1) + (a2 + a3);

    // keypoint disk sum for blocks 0..254 (wave 0 only) — hidden under streaming
    float dsum = 0.f;
    if (blockIdx.x < NKP && tid < 64) {
        const int t = blockIdx.x;
        const float xf = kp[2 * t];
        const float yf = kp[2 * t + 1];
        const bool valid =
            ((xf != 0.f) && (xf != -1.f)) || ((yf != 0.f) && (yf != -1.f));
        if (valid && tid < 49) {
            const int dy = tid / 7 - 3;
            const int dx = tid % 7 - 3;
            if (dy * dy + dx * dx <= 9) {
                const int yy = (int)yf + dy;   // trunc matches astype(int32)
                const int xx = (int)xf + dx;
                if (yy >= 0 && yy < HH && xx >= 0 && xx < WW)
                    dsum = pred[(size_t)t * (HH * WW) + yy * WW + xx];
            }
        }
        #pragma unroll
        for (int off = 32; off > 0; off >>= 1)
            dsum += __shfl_down(dsum, off, 64);
        if (tid == 0)
            ws[DSUM_OFF + t] = (float)(NP - t / NK) * dsum;  // plain store
    }

    // block reduce softplus partials
    #pragma unroll
    for (int off = 32; off > 0; off >>= 1)
        acc += __shfl_down(acc, off, 64);
    __shared__ float wsums[4];
    if ((tid & 63) == 0) wsums[tid >> 6] = acc;
    __syncthreads();
    if (tid == 0)
        ws[blockIdx.x] = wsums[0] + wsums[1] + wsums[2] + wsums[3];
}

// ---- Kernel B: pure reduction of 2040 + 255 floats ------------------------
__global__ __launch_bounds__(256) void finish_kernel(
    const float* __restrict__ ws, float* __restrict__ out) {
    const int tid = threadIdx.x;

    float ssum = 0.f;
    #pragma unroll
    for (int j = 0; j < 8; ++j)          // 2040 = 255*8 < 8*256
    {
        int i = tid + j * TPB;
        if (i < BLOCKS_A) ssum += ws[i];
    }
    float dsum = (tid < NKP) ? ws[DSUM_OFF + tid] : 0.f;

    #pragma unroll
    for (int off = 32; off > 0; off >>= 1) {
        ssum += __shfl_down(ssum, off, 64);
        dsum += __shfl_down(dsum, off, 64);
    }
    __shared__ float sred[4], dred[4];
    if ((tid & 63) == 0) { sred[tid >> 6] = ssum; dred[tid >> 6] = dsum; }
    __syncthreads();

    if (tid == 0) {
        double stot = (double)(sred[0] + sred[1]) + (double)(sred[2] + sred[3]);
        double dtot = (double)(dred[0] + dred[1]) + (double)(dred[2] + dred[3]);
        const double N = (double)NP * NK * HH * WW;
        double heatmap_loss = stot / N - dtot / ((double)NP * N);
        out[0] = (float)(4.0 * heatmap_loss + 0.02);
    }
}

extern "C" void kernel_launch(void* const* d_in, const int* in_sizes, int n_in,
                              void* d_out, int out_size, void* d_ws, size_t ws_size,
                              hipStream_t stream) {
    const float* pred = (const float*)d_in[0];   // [15,17,256,256] fp32
    const float* kp   = (const float*)d_in[2];   // [15,17,2] fp32
    float* out = (float*)d_out;
    float* ws = (float*)d_ws;                    // 2303 floats used, fully written by A

    softplus_partial_kernel<<<BLOCKS_A, TPB, 0, stream>>>(
        (const f32x4*)pred, pred, kp, ws);
    finish_kernel<<<1, TPB, 0, stream>>>(ws, out);
}